// Round 13
// baseline (51.866 us; speedup 1.0000x reference)
//
#include <hip/hip_runtime.h>
#include <math.h>

#pragma clang fp contract(off)

#define NPIX 1024
#define MS 35     // pre-kernel mask-tile stride
#define IPB 4     // images per block (main kernel)

// ---------------------------------------------------------------------------
// 9-tap gaussian (sigma=1, lw=4): phi in f64, normalized with numpy's pairwise
// sum order, cast to f32 — matches jnp.asarray(GAUSS_K, float32).
// ---------------------------------------------------------------------------
__device__ __forceinline__ void compute_gk(float gk[9]) {
    double phi[9];
    #pragma unroll
    for (int t = 0; t < 9; ++t) {
        double d = (double)(t - 4);
        phi[t] = exp(-0.5 * d * d);
    }
    double s = (((phi[0] + phi[1]) + (phi[2] + phi[3])) +
                ((phi[4] + phi[5]) + (phi[6] + phi[7]))) + phi[8];
    #pragma unroll
    for (int t = 0; t < 9; ++t) gk[t] = (float)(phi[t] / s);
}

// ---------------------------------------------------------------------------
// Kernel A (1 block, serial): gk -> ws_gk; 1/(double)(bleed+1e-12) -> ws_blrcp;
// er = erode3x3(mask!=0) & (mag2(batch0) > 0) -> ws_er.   (round-11 proven)
// ---------------------------------------------------------------------------
__global__ __launch_bounds__(256) void canny_pre(const float* __restrict__ x,
                                                 const float* __restrict__ mask,
                                                 double* __restrict__ ws_blrcp,
                                                 unsigned int* __restrict__ ws_er,
                                                 float* __restrict__ ws_gk) {
    __shared__ float APAD[40 * 32];
    __shared__ float BPAD[32 * 40];
    __shared__ float MPAD[34 * MS];
    __shared__ unsigned int er32[32];
    const int tid = threadIdx.x;
    const int i  = tid >> 3;
    const int j0 = (tid & 7) << 2;

    float gk[9];
    compute_gk(gk);
    if (tid < 9) ws_gk[tid] = gk[tid];

    APAD[tid < 128 ? tid : 1024 + tid] = 0.0f;
    { int r = tid >> 3, c8 = tid & 7; BPAD[r * 40 + c8 + (c8 < 4 ? 0 : 32)] = 0.0f; }
    #pragma unroll
    for (int t = 0; t < 5; ++t) { int idx = tid + (t << 8); if (idx < 34 * MS) MPAD[idx] = 0.0f; }
    {
        float4 mk = ((const float4*)mask)[tid];
        *(float4*)&APAD[((i + 4) << 5) + j0] = mk;
        int mbase = (i + 1) * MS + (j0 + 1);
        MPAD[mbase]     = mk.x;
        MPAD[mbase + 1] = mk.y;
        MPAD[mbase + 2] = mk.z;
        MPAD[mbase + 3] = mk.w;
    }
    __syncthreads();   // B1

    {
        float4 acc = make_float4(0.0f, 0.0f, 0.0f, 0.0f);
        #pragma unroll
        for (int t = 0; t < 9; ++t) {
            float4 v = *(const float4*)&APAD[((i + t) << 5) + j0];
            acc.x = __fmaf_rn(gk[t], v.x, acc.x);
            acc.y = __fmaf_rn(gk[t], v.y, acc.y);
            acc.z = __fmaf_rn(gk[t], v.z, acc.z);
            acc.w = __fmaf_rn(gk[t], v.w, acc.w);
        }
        *(float4*)&BPAD[i * 40 + j0 + 4] = acc;
    }
    asm volatile("" ::: "memory");

    float bl4[4];
    {
        const float* bp = &BPAD[i * 40 + j0];
        float4 w0 = *(const float4*)bp;
        float4 w1 = *(const float4*)(bp + 4);
        float4 w2 = *(const float4*)(bp + 8);
        float win[12] = {w0.x, w0.y, w0.z, w0.w, w1.x, w1.y, w1.z, w1.w,
                         w2.x, w2.y, w2.z, w2.w};
        #pragma unroll
        for (int q = 0; q < 4; ++q) {
            float s = 0.0f;
            #pragma unroll
            for (int t = 0; t < 9; ++t) s = __fmaf_rn(gk[t], win[q + t], s);
            bl4[q] = s + 1e-12f;
            ws_blrcp[(i << 5) + j0 + q] = 1.0 / (double)bl4[q];
        }
    }
    bool er2d[4];
    #pragma unroll
    for (int q = 0; q < 4; ++q) {
        int base = (i + 1) * MS + (j0 + q + 1);
        bool e = true;
        #pragma unroll
        for (int di = -1; di <= 1; ++di)
            #pragma unroll
            for (int dj = -1; dj <= 1; ++dj)
                e = e && (MPAD[base + di * MS + dj] != 0.0f);
        er2d[q] = e;
    }
    __syncthreads();   // B2

    {
        const float4* xr = (const float4*)x;
        float4 r4 = xr[tid], g4 = xr[tid + 256], c4 = xr[tid + 512];
        float4 gy;
        gy.x = (r4.x * 0.5f + 0.5f) * 0.299f + (g4.x * 0.5f + 0.5f) * 0.587f + (c4.x * 0.5f + 0.5f) * 0.114f;
        gy.y = (r4.y * 0.5f + 0.5f) * 0.299f + (g4.y * 0.5f + 0.5f) * 0.587f + (c4.y * 0.5f + 0.5f) * 0.114f;
        gy.z = (r4.z * 0.5f + 0.5f) * 0.299f + (g4.z * 0.5f + 0.5f) * 0.587f + (c4.z * 0.5f + 0.5f) * 0.114f;
        gy.w = (r4.w * 0.5f + 0.5f) * 0.299f + (g4.w * 0.5f + 0.5f) * 0.587f + (c4.w * 0.5f + 0.5f) * 0.114f;
        *(float4*)&APAD[((i + 4) << 5) + j0] = gy;
    }
    __syncthreads();   // B3

    {
        float4 acc = make_float4(0.0f, 0.0f, 0.0f, 0.0f);
        #pragma unroll
        for (int t = 0; t < 9; ++t) {
            float4 v = *(const float4*)&APAD[((i + t) << 5) + j0];
            acc.x = __fmaf_rn(gk[t], v.x, acc.x);
            acc.y = __fmaf_rn(gk[t], v.y, acc.y);
            acc.z = __fmaf_rn(gk[t], v.z, acc.z);
            acc.w = __fmaf_rn(gk[t], v.w, acc.w);
        }
        *(float4*)&BPAD[i * 40 + j0 + 4] = acc;
    }
    asm volatile("" ::: "memory");
    {
        const float* bp = &BPAD[i * 40 + j0];
        float4 w0 = *(const float4*)bp;
        float4 w1 = *(const float4*)(bp + 4);
        float4 w2 = *(const float4*)(bp + 8);
        float win[12] = {w0.x, w0.y, w0.z, w0.w, w1.x, w1.y, w1.z, w1.w,
                         w2.x, w2.y, w2.z, w2.w};
        float4 sm4;
        float s;
        s = 0.0f;
        #pragma unroll
        for (int t = 0; t < 9; ++t) s = __fmaf_rn(gk[t], win[0 + t], s);
        sm4.x = s / bl4[0];
        s = 0.0f;
        #pragma unroll
        for (int t = 0; t < 9; ++t) s = __fmaf_rn(gk[t], win[1 + t], s);
        sm4.y = s / bl4[1];
        s = 0.0f;
        #pragma unroll
        for (int t = 0; t < 9; ++t) s = __fmaf_rn(gk[t], win[2 + t], s);
        sm4.z = s / bl4[2];
        s = 0.0f;
        #pragma unroll
        for (int t = 0; t < 9; ++t) s = __fmaf_rn(gk[t], win[3 + t], s);
        sm4.w = s / bl4[3];
        asm volatile("" ::: "memory");
        *(float4*)&BPAD[i * 40 + j0 + 4] = sm4;
    }
    __syncthreads();   // B4

    {
        const int im1 = i > 0 ? i - 1 : 0, ip1 = i < 31 ? i + 1 : 31;
        const bool le = (j0 == 0), re = (j0 == 28);
        float am[6], a0[6], ap[6];
        {
            const float* r = BPAD + im1 * 40 + j0;
            float4 v0 = *(const float4*)r, v1 = *(const float4*)(r + 4), v2 = *(const float4*)(r + 8);
            am[0] = le ? v1.x : v0.w; am[1] = v1.x; am[2] = v1.y; am[3] = v1.z; am[4] = v1.w;
            am[5] = re ? v1.w : v2.x;
        }
        {
            const float* r = BPAD + i * 40 + j0;
            float4 v0 = *(const float4*)r, v1 = *(const float4*)(r + 4), v2 = *(const float4*)(r + 8);
            a0[0] = le ? v1.x : v0.w; a0[1] = v1.x; a0[2] = v1.y; a0[3] = v1.z; a0[4] = v1.w;
            a0[5] = re ? v1.w : v2.x;
        }
        {
            const float* r = BPAD + ip1 * 40 + j0;
            float4 v0 = *(const float4*)r, v1 = *(const float4*)(r + 4), v2 = *(const float4*)(r + 8);
            ap[0] = le ? v1.x : v0.w; ap[1] = v1.x; ap[2] = v1.y; ap[3] = v1.z; ap[4] = v1.w;
            ap[5] = re ? v1.w : v2.x;
        }
        unsigned int en = 0u;
        #pragma unroll
        for (int q = 0; q < 4; ++q) {
            float tm = am[q + 2] - am[q];
            float t0 = a0[q + 2] - a0[q];
            float tp = ap[q + 2] - ap[q];
            float jsob = (tm + 2.0f * t0) + tp;
            float um = ap[q] - am[q];
            float u0 = ap[q + 1] - am[q + 1];
            float up = ap[q + 2] - am[q + 2];
            float isob = (um + 2.0f * u0) + up;
            float m2 = isob * isob + jsob * jsob;
            if (er2d[q] && (m2 > 0.0f)) en |= (1u << (j0 + q));
        }
        #pragma unroll
        for (int mset = 1; mset < 8; mset <<= 1)
            en |= (unsigned int)__shfl_xor((int)en, mset, 64);
        if ((tid & 7) == 0) er32[i] = en;
    }
    __syncthreads();   // B5
    if (tid < 32) ws_er[tid] = er32[tid];
}

// ---------------------------------------------------------------------------
// Kernel B: one block per IPB=4 images, round-12 phase code in a loop.
// One-time init (guards, er, gk, reciprocals); next image's channels are
// register-prefetched before B1 so HBM latency hides under the pipeline.
// B1 of iteration k+1 fences all cross-iteration LDS reuse.
// ---------------------------------------------------------------------------
__global__ __launch_bounds__(256) void canny_main(const float* __restrict__ x,
                                                  const double* __restrict__ ws_blrcp,
                                                  const unsigned int* __restrict__ ws_er,
                                                  const float* __restrict__ ws_gk,
                                                  float* __restrict__ out, int Bn) {
    __shared__ float APAD[40 * 32];    // (r+4)*32 + c ; rows 0-3,36-39 zero
    __shared__ float BPAD[32 * 40];    // r*40 + (c+4) ; cols 0-3,36-39 zero
    __shared__ float MAGT[34 * 40];    // (r+1)*40 + (c+4) ; ring zero
    __shared__ unsigned int er[32], hi32[32], lo32[32];
    const int tid = threadIdx.x;
    const int i  = tid >> 3;           // row 0..31
    const int j0 = (tid & 7) << 2;     // col base 0,4,...,28
    const int l  = tid & 63;
    const int b0 = blockIdx.x * IPB;

    float gk[9];
    #pragma unroll
    for (int t = 0; t < 9; ++t) gk[t] = ws_gk[t];

    double rc[4];
    #pragma unroll
    for (int q = 0; q < 4; ++q) rc[q] = ws_blrcp[(i << 5) + j0 + q];

    // one-time zero guards
    APAD[tid < 128 ? tid : 1024 + tid] = 0.0f;
    { int r = tid >> 3, c8 = tid & 7; BPAD[r * 40 + c8 + (c8 < 4 ? 0 : 32)] = 0.0f; }
    if (tid < 80) MAGT[(tid < 40) ? tid : (33 * 40 + tid - 40)] = 0.0f;
    { int c8 = tid & 7; MAGT[((tid >> 3) + 1) * 40 + c8 + (c8 < 4 ? 0 : 32)] = 0.0f; }
    if (tid < 32) er[tid] = ws_er[tid];

    // prefetch image b0's channels
    float4 pr4, pg4, pc4;
    {
        int b = (b0 < Bn) ? b0 : Bn - 1;
        const float4* xr = (const float4*)(x + (size_t)b * 3 * NPIX);
        pr4 = xr[tid]; pg4 = xr[tid + 256]; pc4 = xr[tid + 512];
    }

    for (int k = 0; k < IPB; ++k) {
        const int bk = b0 + k;
        const int b  = (bk < Bn) ? bk : Bn - 1;

        // gray from prefetched regs -> APAD interior
        {
            float4 r4 = pr4, g4 = pg4, c4 = pc4;
            float4 gy;
            gy.x = (r4.x * 0.5f + 0.5f) * 0.299f + (g4.x * 0.5f + 0.5f) * 0.587f + (c4.x * 0.5f + 0.5f) * 0.114f;
            gy.y = (r4.y * 0.5f + 0.5f) * 0.299f + (g4.y * 0.5f + 0.5f) * 0.587f + (c4.y * 0.5f + 0.5f) * 0.114f;
            gy.z = (r4.z * 0.5f + 0.5f) * 0.299f + (g4.z * 0.5f + 0.5f) * 0.587f + (c4.z * 0.5f + 0.5f) * 0.114f;
            gy.w = (r4.w * 0.5f + 0.5f) * 0.299f + (g4.w * 0.5f + 0.5f) * 0.587f + (c4.w * 0.5f + 0.5f) * 0.114f;
            *(float4*)&APAD[((i + 4) << 5) + j0] = gy;
        }
        // prefetch next image (loads in flight across the whole pipeline)
        if (k + 1 < IPB) {
            int bn = (bk + 1 < Bn) ? bk + 1 : Bn - 1;
            const float4* xn = (const float4*)(x + (size_t)bn * 3 * NPIX);
            pr4 = xn[tid]; pg4 = xn[tid + 256]; pc4 = xn[tid + 512];
        }
        __syncthreads();   // B1

        // blur H -> BPAD interior
        {
            float4 acc = make_float4(0.0f, 0.0f, 0.0f, 0.0f);
            #pragma unroll
            for (int t = 0; t < 9; ++t) {
                float4 v = *(const float4*)&APAD[((i + t) << 5) + j0];
                acc.x = __fmaf_rn(gk[t], v.x, acc.x);
                acc.y = __fmaf_rn(gk[t], v.y, acc.y);
                acc.z = __fmaf_rn(gk[t], v.z, acc.z);
                acc.w = __fmaf_rn(gk[t], v.w, acc.w);
            }
            *(float4*)&BPAD[i * 40 + j0 + 4] = acc;
        }
        asm volatile("" ::: "memory");

        // blur W + divide via f64 reciprocal -> sm -> BPAD (same-octet)
        {
            const float* bp = &BPAD[i * 40 + j0];
            float4 w0 = *(const float4*)bp;
            float4 w1 = *(const float4*)(bp + 4);
            float4 w2 = *(const float4*)(bp + 8);
            float win[12] = {w0.x, w0.y, w0.z, w0.w, w1.x, w1.y, w1.z, w1.w,
                             w2.x, w2.y, w2.z, w2.w};
            float4 sm4;
            float s;
            s = 0.0f;
            #pragma unroll
            for (int t = 0; t < 9; ++t) s = __fmaf_rn(gk[t], win[0 + t], s);
            sm4.x = (float)((double)s * rc[0]);
            s = 0.0f;
            #pragma unroll
            for (int t = 0; t < 9; ++t) s = __fmaf_rn(gk[t], win[1 + t], s);
            sm4.y = (float)((double)s * rc[1]);
            s = 0.0f;
            #pragma unroll
            for (int t = 0; t < 9; ++t) s = __fmaf_rn(gk[t], win[2 + t], s);
            sm4.z = (float)((double)s * rc[2]);
            s = 0.0f;
            #pragma unroll
            for (int t = 0; t < 9; ++t) s = __fmaf_rn(gk[t], win[3 + t], s);
            sm4.w = (float)((double)s * rc[3]);
            asm volatile("" ::: "memory");
            *(float4*)&BPAD[i * 40 + j0 + 4] = sm4;
        }
        __syncthreads();   // B2

        // fused sobel + mag: sm from BPAD, mag -> MAGT (one b128) + regs
        float jsr[4], isr[4], mr[4];
        {
            const int im1 = i > 0 ? i - 1 : 0, ip1 = i < 31 ? i + 1 : 31;
            const bool le = (j0 == 0), re = (j0 == 28);
            float am[6], a0[6], ap[6];
            {
                const float* r = BPAD + im1 * 40 + j0;
                float4 v0 = *(const float4*)r, v1 = *(const float4*)(r + 4), v2 = *(const float4*)(r + 8);
                am[0] = le ? v1.x : v0.w; am[1] = v1.x; am[2] = v1.y; am[3] = v1.z; am[4] = v1.w;
                am[5] = re ? v1.w : v2.x;
            }
            {
                const float* r = BPAD + i * 40 + j0;
                float4 v0 = *(const float4*)r, v1 = *(const float4*)(r + 4), v2 = *(const float4*)(r + 8);
                a0[0] = le ? v1.x : v0.w; a0[1] = v1.x; a0[2] = v1.y; a0[3] = v1.z; a0[4] = v1.w;
                a0[5] = re ? v1.w : v2.x;
            }
            {
                const float* r = BPAD + ip1 * 40 + j0;
                float4 v0 = *(const float4*)r, v1 = *(const float4*)(r + 4), v2 = *(const float4*)(r + 8);
                ap[0] = le ? v1.x : v0.w; ap[1] = v1.x; ap[2] = v1.y; ap[3] = v1.z; ap[4] = v1.w;
                ap[5] = re ? v1.w : v2.x;
            }
            #pragma unroll
            for (int q = 0; q < 4; ++q) {
                float tm = am[q + 2] - am[q];
                float t0 = a0[q + 2] - a0[q];
                float tp = ap[q + 2] - ap[q];
                float jsob = (tm + 2.0f * t0) + tp;
                float um = ap[q] - am[q];
                float u0 = ap[q + 1] - am[q + 1];
                float up = ap[q + 2] - am[q + 2];
                float isob = (um + 2.0f * u0) + up;
                jsr[q] = jsob; isr[q] = isob;
                mr[q] = sqrtf((isob * isob + jsob * jsob) + 1e-9f);
            }
            *(float4*)&MAGT[(i + 1) * 40 + j0 + 4] = make_float4(mr[0], mr[1], mr[2], mr[3]);
        }
        __syncthreads();   // B3

        // branchless NMS from b128 mag windows; neighbor pick via selects
        {
            float wm[6], w0r[6], wp[6];
            {
                const float* r = MAGT + i * 40 + j0;          // mag(i-1, ...)
                float4 v0 = *(const float4*)r, v1 = *(const float4*)(r + 4), v2 = *(const float4*)(r + 8);
                wm[0] = v0.w; wm[1] = v1.x; wm[2] = v1.y; wm[3] = v1.z; wm[4] = v1.w; wm[5] = v2.x;
            }
            {
                const float* r = MAGT + (i + 1) * 40 + j0;    // mag(i, ...)
                float4 v0 = *(const float4*)r, v1 = *(const float4*)(r + 4), v2 = *(const float4*)(r + 8);
                w0r[0] = v0.w; w0r[1] = v1.x; w0r[2] = v1.y; w0r[3] = v1.z; w0r[4] = v1.w; w0r[5] = v2.x;
            }
            {
                const float* r = MAGT + (i + 2) * 40 + j0;    // mag(i+1, ...)
                float4 v0 = *(const float4*)r, v1 = *(const float4*)(r + 4), v2 = *(const float4*)(r + 8);
                wp[0] = v0.w; wp[1] = v1.x; wp[2] = v1.y; wp[3] = v1.z; wp[4] = v1.w; wp[5] = v2.x;
            }
            unsigned int ew = er[i];
            unsigned int hn = 0u, ln = 0u;
            #pragma unroll
            for (int q = 0; q < 4; ++q) {
                int j = j0 + q;
                float iv = isr[q], jv = jsr[q], m = mr[q];
                float ai = fabsf(iv), aj = fabsf(jv);
                bool same = (iv >= 0.0f && jv >= 0.0f) || (iv <= 0.0f && jv <= 0.0f);
                bool opp  = (iv <= 0.0f && jv >= 0.0f) || (iv >= 0.0f && jv <= 0.0f);
                bool age  = (ai >= aj), ale = (ai <= aj);
                int oct = (opp && age) ? 3 : (opp && ale) ? 2 : (same && ale) ? 1 : 0;
                float ais = ai > 0.0f ? ai : 1.0f;
                float ajs = aj > 0.0f ? aj : 1.0f;
                float num = (oct == 3 || oct == 0) ? aj : ai;
                float den = (oct == 3) ? ais : (oct == 0) ? (ai + 1e-9f) : ajs;
                float wq = num / den;
                float omw = 1.0f - wq;
                bool p2dn = (oct < 2);
                float p2v = p2dn ? wp[q + 2] : wm[q + 2];
                float m2v = p2dn ? wm[q]     : wp[q];
                float p1v = (oct == 0) ? wp[q + 1] : (oct == 3) ? wm[q + 1] : w0r[q + 2];
                float m1v = (oct == 0) ? wm[q + 1] : (oct == 3) ? wp[q + 1] : w0r[q];
                float ipv = p2v * wq + p1v * omw;
                float imv = m2v * wq + m1v * omw;
                bool lm = (ipv <= m) && (imv <= m);
                bool eb = (ew >> j) & 1u;
                if (lm && eb && (m >= 0.2f)) hn |= (1u << j);
                if (lm && eb && (m >= 0.1f)) ln |= (1u << j);
            }
            #pragma unroll
            for (int mset = 1; mset < 8; mset <<= 1) {
                hn |= (unsigned int)__shfl_xor((int)hn, mset, 64);
                ln |= (unsigned int)__shfl_xor((int)ln, mset, 64);
            }
            if ((tid & 7) == 0) { hi32[i] = hn; lo32[i] = ln; }
        }
        __syncthreads();   // B4

        // hysteresis flood on ALL waves (redundant, identical per wave)
        unsigned int cur;
        {
            unsigned int lw = (l < 32) ? lo32[l] : 0u;
            cur             = (l < 32) ? hi32[l] : 0u;
            for (;;) {
                unsigned int sp  = cur | (cur << 1) | (cur >> 1);
                unsigned int upv = (unsigned int)__shfl((int)sp, (l + 63) & 63, 64);
                if (l == 0) upv = 0u;
                unsigned int dnv = (unsigned int)__shfl((int)sp, (l + 1) & 63, 64);
                unsigned int nxt = (sp | upv | dnv) & lw;
                bool ch = (nxt != cur);
                cur = nxt;
                if (__ballot((int)ch) == 0ull) break;
            }
        }

        // output: row word via shfl from lane i of own wave; float4 store
        {
            unsigned int wd = (unsigned int)__shfl((int)cur, i, 64);
            float4 o;
            o.x = ((wd >> (j0    )) & 1u) ? 1.0f : -1.0f;
            o.y = ((wd >> (j0 + 1)) & 1u) ? 1.0f : -1.0f;
            o.z = ((wd >> (j0 + 2)) & 1u) ? 1.0f : -1.0f;
            o.w = ((wd >> (j0 + 3)) & 1u) ? 1.0f : -1.0f;
            ((float4*)(out + (size_t)b * NPIX))[tid] = o;
        }
        // B1 of next iteration fences LDS reuse (gray write vs this iter's reads)
    }
}

extern "C" void kernel_launch(void* const* d_in, const int* in_sizes, int n_in,
                              void* d_out, int out_size, void* d_ws, size_t ws_size,
                              hipStream_t stream) {
    const float* x    = (const float*)d_in[0];
    const float* mask = (const float*)d_in[1];
    float* out        = (float*)d_out;
    double* ws_blrcp  = (double*)d_ws;                       // 1024 doubles
    unsigned int* ws_er = (unsigned int*)(ws_blrcp + NPIX);  // 32 u32
    float* ws_gk      = (float*)(ws_er + 32);                // 9 floats
    int Bn = in_sizes[0] / (3 * NPIX);

    hipLaunchKernelGGL(canny_pre, dim3(1), dim3(256), 0, stream, x, mask, ws_blrcp, ws_er, ws_gk);
    hipLaunchKernelGGL(canny_main, dim3((Bn + IPB - 1) / IPB), dim3(256), 0, stream,
                       x, ws_blrcp, ws_er, ws_gk, out, Bn);
}

// Round 14
// 46.859 us; speedup vs baseline: 1.1068x; 1.1068x over previous
//
#include <hip/hip_runtime.h>
#include <math.h>

#pragma clang fp contract(off)

#define NPIX 1024
#define MS 35   // MPAD row stride (35 keeps worst aliasing at 2-way)

// ---------------------------------------------------------------------------
// 9-tap gaussian (sigma=1, lw=4): phi in f64, normalized with numpy's pairwise
// sum order, cast to f32 — matches jnp.asarray(GAUSS_K, float32).
// ---------------------------------------------------------------------------
__device__ __forceinline__ void compute_gk(float gk[9]) {
    double phi[9];
    #pragma unroll
    for (int t = 0; t < 9; ++t) {
        double d = (double)(t - 4);
        phi[t] = exp(-0.5 * d * d);
    }
    double s = (((phi[0] + phi[1]) + (phi[2] + phi[3])) +
                ((phi[4] + phi[5]) + (phi[6] + phi[7]))) + phi[8];
    #pragma unroll
    for (int t = 0; t < 9; ++t) gk[t] = (float)(phi[t] / s);
}

// ---------------------------------------------------------------------------
// Kernel A (1 block, serial): gk -> ws_gk; 1/(double)(bleed+1e-12) -> ws_blrcp;
// er = erode3x3(mask!=0) & (mag2(batch0) > 0) -> ws_er.
// (Correctly-rounded f32 division s/bl == fl32(fl64(s)*fl64(1/bl)) by the
//  exclusion-zone lemma — quotient of two 24-bit floats is never a midpoint.)
// ---------------------------------------------------------------------------
__global__ __launch_bounds__(256) void canny_pre(const float* __restrict__ x,
                                                 const float* __restrict__ mask,
                                                 double* __restrict__ ws_blrcp,
                                                 unsigned int* __restrict__ ws_er,
                                                 float* __restrict__ ws_gk) {
    __shared__ float APAD[40 * 32];    // (r+4)*32 + c ; rows 0-3,36-39 zero
    __shared__ float BPAD[32 * 40];    // r*40 + (c+4) ; cols 0-3,36-39 zero
    __shared__ float MPAD[34 * MS];    // (r+1)*MS + (c+1) ; ring zero (mask tile)
    __shared__ unsigned int er32[32];
    const int tid = threadIdx.x;
    const int i  = tid >> 3;
    const int j0 = (tid & 7) << 2;

    float gk[9];
    compute_gk(gk);
    if (tid < 9) ws_gk[tid] = gk[tid];

    // guards + mask tiles
    APAD[tid < 128 ? tid : 1024 + tid] = 0.0f;
    { int r = tid >> 3, c8 = tid & 7; BPAD[r * 40 + c8 + (c8 < 4 ? 0 : 32)] = 0.0f; }
    #pragma unroll
    for (int t = 0; t < 5; ++t) { int idx = tid + (t << 8); if (idx < 34 * MS) MPAD[idx] = 0.0f; }
    {
        float4 mk = ((const float4*)mask)[tid];
        *(float4*)&APAD[((i + 4) << 5) + j0] = mk;
        int mbase = (i + 1) * MS + (j0 + 1);
        MPAD[mbase]     = mk.x;
        MPAD[mbase + 1] = mk.y;
        MPAD[mbase + 2] = mk.z;
        MPAD[mbase + 3] = mk.w;
    }
    __syncthreads();   // B1

    // mask blur H -> BPAD interior
    {
        float4 acc = make_float4(0.0f, 0.0f, 0.0f, 0.0f);
        #pragma unroll
        for (int t = 0; t < 9; ++t) {
            float4 v = *(const float4*)&APAD[((i + t) << 5) + j0];
            acc.x = __fmaf_rn(gk[t], v.x, acc.x);
            acc.y = __fmaf_rn(gk[t], v.y, acc.y);
            acc.z = __fmaf_rn(gk[t], v.z, acc.z);
            acc.w = __fmaf_rn(gk[t], v.w, acc.w);
        }
        *(float4*)&BPAD[i * 40 + j0 + 4] = acc;
    }
    asm volatile("" ::: "memory");

    // mask blur W (same-octet BPAD reads) -> bleed regs; rcp -> global; erosion
    float bl4[4];
    {
        const float* bp = &BPAD[i * 40 + j0];
        float4 w0 = *(const float4*)bp;
        float4 w1 = *(const float4*)(bp + 4);
        float4 w2 = *(const float4*)(bp + 8);
        float win[12] = {w0.x, w0.y, w0.z, w0.w, w1.x, w1.y, w1.z, w1.w,
                         w2.x, w2.y, w2.z, w2.w};
        #pragma unroll
        for (int q = 0; q < 4; ++q) {
            float s = 0.0f;
            #pragma unroll
            for (int t = 0; t < 9; ++t) s = __fmaf_rn(gk[t], win[q + t], s);
            bl4[q] = s + 1e-12f;           // the exact f32 divisor
            ws_blrcp[(i << 5) + j0 + q] = 1.0 / (double)bl4[q];
        }
    }
    bool er2d[4];
    #pragma unroll
    for (int q = 0; q < 4; ++q) {
        int base = (i + 1) * MS + (j0 + q + 1);
        bool e = true;
        #pragma unroll
        for (int di = -1; di <= 1; ++di)
            #pragma unroll
            for (int dj = -1; dj <= 1; ++dj)
                e = e && (MPAD[base + di * MS + dj] != 0.0f);
        er2d[q] = e;
    }
    __syncthreads();   // B2

    // gray (image 0) -> APAD interior
    {
        const float4* xr = (const float4*)x;
        float4 r4 = xr[tid], g4 = xr[tid + 256], c4 = xr[tid + 512];
        float4 gy;
        gy.x = (r4.x * 0.5f + 0.5f) * 0.299f + (g4.x * 0.5f + 0.5f) * 0.587f + (c4.x * 0.5f + 0.5f) * 0.114f;
        gy.y = (r4.y * 0.5f + 0.5f) * 0.299f + (g4.y * 0.5f + 0.5f) * 0.587f + (c4.y * 0.5f + 0.5f) * 0.114f;
        gy.z = (r4.z * 0.5f + 0.5f) * 0.299f + (g4.z * 0.5f + 0.5f) * 0.587f + (c4.z * 0.5f + 0.5f) * 0.114f;
        gy.w = (r4.w * 0.5f + 0.5f) * 0.299f + (g4.w * 0.5f + 0.5f) * 0.587f + (c4.w * 0.5f + 0.5f) * 0.114f;
        *(float4*)&APAD[((i + 4) << 5) + j0] = gy;
    }
    __syncthreads();   // B3

    // gray blur H -> BPAD; (fence); blur W + f32 div -> sm -> BPAD (same-octet)
    {
        float4 acc = make_float4(0.0f, 0.0f, 0.0f, 0.0f);
        #pragma unroll
        for (int t = 0; t < 9; ++t) {
            float4 v = *(const float4*)&APAD[((i + t) << 5) + j0];
            acc.x = __fmaf_rn(gk[t], v.x, acc.x);
            acc.y = __fmaf_rn(gk[t], v.y, acc.y);
            acc.z = __fmaf_rn(gk[t], v.z, acc.z);
            acc.w = __fmaf_rn(gk[t], v.w, acc.w);
        }
        *(float4*)&BPAD[i * 40 + j0 + 4] = acc;
    }
    asm volatile("" ::: "memory");
    {
        const float* bp = &BPAD[i * 40 + j0];
        float4 w0 = *(const float4*)bp;
        float4 w1 = *(const float4*)(bp + 4);
        float4 w2 = *(const float4*)(bp + 8);
        float win[12] = {w0.x, w0.y, w0.z, w0.w, w1.x, w1.y, w1.z, w1.w,
                         w2.x, w2.y, w2.z, w2.w};
        float4 sm4;
        float s;
        s = 0.0f;
        #pragma unroll
        for (int t = 0; t < 9; ++t) s = __fmaf_rn(gk[t], win[0 + t], s);
        sm4.x = s / bl4[0];
        s = 0.0f;
        #pragma unroll
        for (int t = 0; t < 9; ++t) s = __fmaf_rn(gk[t], win[1 + t], s);
        sm4.y = s / bl4[1];
        s = 0.0f;
        #pragma unroll
        for (int t = 0; t < 9; ++t) s = __fmaf_rn(gk[t], win[2 + t], s);
        sm4.z = s / bl4[2];
        s = 0.0f;
        #pragma unroll
        for (int t = 0; t < 9; ++t) s = __fmaf_rn(gk[t], win[3 + t], s);
        sm4.w = s / bl4[3];
        asm volatile("" ::: "memory");
        *(float4*)&BPAD[i * 40 + j0 + 4] = sm4;
    }
    __syncthreads();   // B4

    // sobel -> mag2; er bits; octet reduce; leaders -> er32
    {
        const int im1 = i > 0 ? i - 1 : 0, ip1 = i < 31 ? i + 1 : 31;
        const bool le = (j0 == 0), re = (j0 == 28);
        float am[6], a0[6], ap[6];
        {
            const float* r = BPAD + im1 * 40 + j0;
            float4 v0 = *(const float4*)r, v1 = *(const float4*)(r + 4), v2 = *(const float4*)(r + 8);
            am[0] = le ? v1.x : v0.w; am[1] = v1.x; am[2] = v1.y; am[3] = v1.z; am[4] = v1.w;
            am[5] = re ? v1.w : v2.x;
        }
        {
            const float* r = BPAD + i * 40 + j0;
            float4 v0 = *(const float4*)r, v1 = *(const float4*)(r + 4), v2 = *(const float4*)(r + 8);
            a0[0] = le ? v1.x : v0.w; a0[1] = v1.x; a0[2] = v1.y; a0[3] = v1.z; a0[4] = v1.w;
            a0[5] = re ? v1.w : v2.x;
        }
        {
            const float* r = BPAD + ip1 * 40 + j0;
            float4 v0 = *(const float4*)r, v1 = *(const float4*)(r + 4), v2 = *(const float4*)(r + 8);
            ap[0] = le ? v1.x : v0.w; ap[1] = v1.x; ap[2] = v1.y; ap[3] = v1.z; ap[4] = v1.w;
            ap[5] = re ? v1.w : v2.x;
        }
        unsigned int en = 0u;
        #pragma unroll
        for (int q = 0; q < 4; ++q) {
            float tm = am[q + 2] - am[q];
            float t0 = a0[q + 2] - a0[q];
            float tp = ap[q + 2] - ap[q];
            float jsob = (tm + 2.0f * t0) + tp;
            float um = ap[q] - am[q];
            float u0 = ap[q + 1] - am[q + 1];
            float up = ap[q + 2] - am[q + 2];
            float isob = (um + 2.0f * u0) + up;
            float m2 = isob * isob + jsob * jsob;   // isob^2 + jsob^2, ref order
            if (er2d[q] && (m2 > 0.0f)) en |= (1u << (j0 + q));
        }
        #pragma unroll
        for (int mset = 1; mset < 8; mset <<= 1)
            en |= (unsigned int)__shfl_xor((int)en, mset, 64);
        if ((tid & 7) == 0) er32[i] = en;
    }
    __syncthreads();   // B5
    if (tid < 32) ws_er[tid] = er32[tid];
}

// ---------------------------------------------------------------------------
// Kernel B: one block per image, 4 barriers (round-11 best-of structure).
// Bleed division via precomputed f64 reciprocal (bit-exact).
// MPAD: only the 132-cell guard ring is zeroed.
// ---------------------------------------------------------------------------
__global__ __launch_bounds__(256) void canny_main(const float* __restrict__ x,
                                                  const double* __restrict__ ws_blrcp,
                                                  const unsigned int* __restrict__ ws_er,
                                                  const float* __restrict__ ws_gk,
                                                  float* __restrict__ out) {
    __shared__ float APAD[40 * 32];    // (r+4)*32 + c ; rows 0-3,36-39 zero
    __shared__ float BPAD[32 * 40];    // r*40 + (c+4) ; cols 0-3,36-39 zero
    __shared__ float MPAD[34 * MS];    // (r+1)*MS + (c+1) ; ring zero
    __shared__ unsigned int er[32], hi32[32], lo32[32];
    const int tid = threadIdx.x;
    const int b = blockIdx.x;
    const int i  = tid >> 3;           // row 0..31
    const int j0 = (tid & 7) << 2;     // col base 0,4,...,28
    const int l  = tid & 63;

    float gk[9];
    #pragma unroll
    for (int t = 0; t < 9; ++t) gk[t] = ws_gk[t];

    // hoisted bleed reciprocals (needed in blurW)
    double rc[4];
    #pragma unroll
    for (int q = 0; q < 4; ++q) rc[q] = ws_blrcp[(i << 5) + j0 + q];

    // zero guards (MPAD: ring cells only)
    APAD[tid < 128 ? tid : 1024 + tid] = 0.0f;
    { int r = tid >> 3, c8 = tid & 7; BPAD[r * 40 + c8 + (c8 < 4 ? 0 : 32)] = 0.0f; }
    if (tid < 132) {
        int idx;
        if (tid < 34)       idx = tid;                    // row 0, cols 0..33
        else if (tid < 68)  idx = 33 * MS + (tid - 34);   // row 33
        else if (tid < 100) idx = (tid - 67) * MS;        // col 0, rows 1..32
        else                idx = (tid - 99) * MS + 33;   // col 33, rows 1..32
        MPAD[idx] = 0.0f;
    }
    if (tid < 32) er[tid] = ws_er[tid];

    // gray: float4 channel loads -> APAD interior
    {
        const float4* xr = (const float4*)(x + (size_t)b * 3 * NPIX);
        float4 r4 = xr[tid], g4 = xr[tid + 256], c4 = xr[tid + 512];
        float4 gy;
        gy.x = (r4.x * 0.5f + 0.5f) * 0.299f + (g4.x * 0.5f + 0.5f) * 0.587f + (c4.x * 0.5f + 0.5f) * 0.114f;
        gy.y = (r4.y * 0.5f + 0.5f) * 0.299f + (g4.y * 0.5f + 0.5f) * 0.587f + (c4.y * 0.5f + 0.5f) * 0.114f;
        gy.z = (r4.z * 0.5f + 0.5f) * 0.299f + (g4.z * 0.5f + 0.5f) * 0.587f + (c4.z * 0.5f + 0.5f) * 0.114f;
        gy.w = (r4.w * 0.5f + 0.5f) * 0.299f + (g4.w * 0.5f + 0.5f) * 0.587f + (c4.w * 0.5f + 0.5f) * 0.114f;
        *(float4*)&APAD[((i + 4) << 5) + j0] = gy;
    }
    __syncthreads();   // B1

    // blur H (over rows): 9x b128, FMA chain ascending -> BPAD interior
    {
        float4 acc = make_float4(0.0f, 0.0f, 0.0f, 0.0f);
        #pragma unroll
        for (int t = 0; t < 9; ++t) {
            float4 v = *(const float4*)&APAD[((i + t) << 5) + j0];
            acc.x = __fmaf_rn(gk[t], v.x, acc.x);
            acc.y = __fmaf_rn(gk[t], v.y, acc.y);
            acc.z = __fmaf_rn(gk[t], v.z, acc.z);
            acc.w = __fmaf_rn(gk[t], v.w, acc.w);
        }
        *(float4*)&BPAD[i * 40 + j0 + 4] = acc;
    }
    asm volatile("" ::: "memory");

    // blur W + divide-by-constant via f64 reciprocal (bit-exact) -> sm -> BPAD
    {
        const float* bp = &BPAD[i * 40 + j0];     // window cols j0-4 .. j0+7
        float4 w0 = *(const float4*)bp;
        float4 w1 = *(const float4*)(bp + 4);
        float4 w2 = *(const float4*)(bp + 8);
        float win[12] = {w0.x, w0.y, w0.z, w0.w, w1.x, w1.y, w1.z, w1.w,
                         w2.x, w2.y, w2.z, w2.w};
        float4 sm4;
        float s;
        s = 0.0f;
        #pragma unroll
        for (int t = 0; t < 9; ++t) s = __fmaf_rn(gk[t], win[0 + t], s);
        sm4.x = (float)((double)s * rc[0]);
        s = 0.0f;
        #pragma unroll
        for (int t = 0; t < 9; ++t) s = __fmaf_rn(gk[t], win[1 + t], s);
        sm4.y = (float)((double)s * rc[1]);
        s = 0.0f;
        #pragma unroll
        for (int t = 0; t < 9; ++t) s = __fmaf_rn(gk[t], win[2 + t], s);
        sm4.z = (float)((double)s * rc[2]);
        s = 0.0f;
        #pragma unroll
        for (int t = 0; t < 9; ++t) s = __fmaf_rn(gk[t], win[3 + t], s);
        sm4.w = (float)((double)s * rc[3]);
        asm volatile("" ::: "memory");
        *(float4*)&BPAD[i * 40 + j0 + 4] = sm4;   // reads above precede (same wave)
    }
    __syncthreads();   // B2

    // fused sobel + mag: sm from BPAD (stride 40, col+4), mag -> MPAD + regs
    float jsr[4], isr[4], mr[4];
    {
        const int im1 = i > 0 ? i - 1 : 0, ip1 = i < 31 ? i + 1 : 31;
        const bool le = (j0 == 0), re = (j0 == 28);
        float am[6], a0[6], ap[6];
        {
            const float* r = BPAD + im1 * 40 + j0;
            float4 v0 = *(const float4*)r, v1 = *(const float4*)(r + 4), v2 = *(const float4*)(r + 8);
            am[0] = le ? v1.x : v0.w; am[1] = v1.x; am[2] = v1.y; am[3] = v1.z; am[4] = v1.w;
            am[5] = re ? v1.w : v2.x;
        }
        {
            const float* r = BPAD + i * 40 + j0;
            float4 v0 = *(const float4*)r, v1 = *(const float4*)(r + 4), v2 = *(const float4*)(r + 8);
            a0[0] = le ? v1.x : v0.w; a0[1] = v1.x; a0[2] = v1.y; a0[3] = v1.z; a0[4] = v1.w;
            a0[5] = re ? v1.w : v2.x;
        }
        {
            const float* r = BPAD + ip1 * 40 + j0;
            float4 v0 = *(const float4*)r, v1 = *(const float4*)(r + 4), v2 = *(const float4*)(r + 8);
            ap[0] = le ? v1.x : v0.w; ap[1] = v1.x; ap[2] = v1.y; ap[3] = v1.z; ap[4] = v1.w;
            ap[5] = re ? v1.w : v2.x;
        }
        #pragma unroll
        for (int q = 0; q < 4; ++q) {
            float tm = am[q + 2] - am[q];
            float t0 = a0[q + 2] - a0[q];
            float tp = ap[q + 2] - ap[q];
            float jsob = (tm + 2.0f * t0) + tp;
            float um = ap[q] - am[q];
            float u0 = ap[q + 1] - am[q + 1];
            float up = ap[q + 2] - am[q + 2];
            float isob = (um + 2.0f * u0) + up;
            jsr[q] = jsob; isr[q] = isob;
            float m = sqrtf((isob * isob + jsob * jsob) + 1e-9f);
            mr[q] = m;
            MPAD[(i + 1) * MS + (j0 + q + 1)] = m;
        }
    }
    __syncthreads();   // B3

    // branchless NMS; nibble masks + shfl_xor OR over the 8-lane row octet
    {
        unsigned int ew = er[i];
        unsigned int hn = 0u, ln = 0u;
        #pragma unroll
        for (int q = 0; q < 4; ++q) {
            int j = j0 + q;
            float iv = isr[q], jv = jsr[q], m = mr[q];
            float ai = fabsf(iv), aj = fabsf(jv);
            bool same = (iv >= 0.0f && jv >= 0.0f) || (iv <= 0.0f && jv <= 0.0f);
            bool opp  = (iv <= 0.0f && jv >= 0.0f) || (iv >= 0.0f && jv <= 0.0f);
            bool age  = (ai >= aj), ale = (ai <= aj);
            int oct = (opp && age) ? 3 : (opp && ale) ? 2 : (same && ale) ? 1 : 0;
            float ais = ai > 0.0f ? ai : 1.0f;
            float ajs = aj > 0.0f ? aj : 1.0f;
            float num = (oct == 3 || oct == 0) ? aj : ai;
            float den = (oct == 3) ? ais : (oct == 0) ? (ai + 1e-9f) : ajs;
            float wq = num / den;
            float omw = 1.0f - wq;
            int p2i = (oct >= 2) ? -1 : 1;
            int p1i = (oct == 0) ? 1 : (oct == 3) ? -1 : 0;
            int p1j = (oct == 1 || oct == 2) ? 1 : 0;
            int base = (i + 1) * MS + (j + 1);
            float ipv = MPAD[base + p2i * MS + 1] * wq + MPAD[base + p1i * MS + p1j] * omw;
            float imv = MPAD[base - p2i * MS - 1] * wq + MPAD[base - p1i * MS - p1j] * omw;
            bool lm = (ipv <= m) && (imv <= m);
            bool eb = (ew >> j) & 1u;
            if (lm && eb && (m >= 0.2f)) hn |= (1u << j);
            if (lm && eb && (m >= 0.1f)) ln |= (1u << j);
        }
        #pragma unroll
        for (int mset = 1; mset < 8; mset <<= 1) {
            hn |= (unsigned int)__shfl_xor((int)hn, mset, 64);
            ln |= (unsigned int)__shfl_xor((int)ln, mset, 64);
        }
        if ((tid & 7) == 0) { hi32[i] = hn; lo32[i] = ln; }
    }
    __syncthreads();   // B4

    // hysteresis flood on ALL waves (redundant, identical result per wave)
    unsigned int cur;
    {
        unsigned int lw = (l < 32) ? lo32[l] : 0u;
        cur             = (l < 32) ? hi32[l] : 0u;
        for (;;) {
            unsigned int sp  = cur | (cur << 1) | (cur >> 1);
            unsigned int upv = (unsigned int)__shfl((int)sp, (l + 63) & 63, 64);
            if (l == 0) upv = 0u;
            unsigned int dnv = (unsigned int)__shfl((int)sp, (l + 1) & 63, 64);
            unsigned int nxt = (sp | upv | dnv) & lw;
            bool ch = (nxt != cur);
            cur = nxt;
            if (__ballot((int)ch) == 0ull) break;
        }
    }

    // output: row word via shfl from lane i of own wave; float4 store
    {
        unsigned int wd = (unsigned int)__shfl((int)cur, i, 64);
        float4 o;
        o.x = ((wd >> (j0    )) & 1u) ? 1.0f : -1.0f;
        o.y = ((wd >> (j0 + 1)) & 1u) ? 1.0f : -1.0f;
        o.z = ((wd >> (j0 + 2)) & 1u) ? 1.0f : -1.0f;
        o.w = ((wd >> (j0 + 3)) & 1u) ? 1.0f : -1.0f;
        ((float4*)(out + (size_t)b * NPIX))[tid] = o;
    }
}

extern "C" void kernel_launch(void* const* d_in, const int* in_sizes, int n_in,
                              void* d_out, int out_size, void* d_ws, size_t ws_size,
                              hipStream_t stream) {
    const float* x    = (const float*)d_in[0];
    const float* mask = (const float*)d_in[1];
    float* out        = (float*)d_out;
    double* ws_blrcp  = (double*)d_ws;                       // 1024 doubles
    unsigned int* ws_er = (unsigned int*)(ws_blrcp + NPIX);  // 32 u32
    float* ws_gk      = (float*)(ws_er + 32);                // 9 floats
    int Bn = in_sizes[0] / (3 * NPIX);

    hipLaunchKernelGGL(canny_pre, dim3(1), dim3(256), 0, stream, x, mask, ws_blrcp, ws_er, ws_gk);
    hipLaunchKernelGGL(canny_main, dim3(Bn), dim3(256), 0, stream, x, ws_blrcp, ws_er, ws_gk, out);
}